// Round 3
// baseline (927.954 us; speedup 1.0000x reference)
//
#include <hip/hip_runtime.h>

typedef unsigned short u16;
typedef unsigned int u32;
typedef __attribute__((ext_vector_type(8))) short short8;
typedef __attribute__((ext_vector_type(4))) float f32x4;
typedef __attribute__((ext_vector_type(4))) unsigned short u16x4;

__device__ __forceinline__ u16 f2bf(float f) {
    u32 u = __float_as_uint(f);
    return (u16)((u + 0x7FFFu + ((u >> 16) & 1u)) >> 16);
}

// ---------------------------------------------------------------------------
// Kernel 0a: NCHW fp32 -> NHWC bf16 (unchanged from R2; ~40 us est.)
// ---------------------------------------------------------------------------
__global__ __launch_bounds__(256) void nchw2nhwc(const float* __restrict__ x,
                                                 u16* __restrict__ xb) {
    __shared__ u16 t[64 * 72];
    const int b   = blockIdx.x;
    const int n   = b >> 8;
    const int icb = (b >> 6) & 3;
    const int pxb = b & 63;
    const int ic0 = icb * 64, px0 = pxb * 64;
    const int tid = threadIdx.x;

    const int icq = tid >> 4;
    const int px4 = (tid & 15) * 4;
    const float* src = x + (size_t)(n * 256 + ic0 + icq * 4) * 4096 + px0 + px4;
    f32x4 v[4];
#pragma unroll
    for (int rr = 0; rr < 4; ++rr) v[rr] = *(const f32x4*)(src + (size_t)rr * 4096);
#pragma unroll
    for (int j = 0; j < 4; ++j) {
        u16x4 p;
        p.x = f2bf(v[0][j]); p.y = f2bf(v[1][j]);
        p.z = f2bf(v[2][j]); p.w = f2bf(v[3][j]);
        *(u16x4*)(t + (px4 + j) * 72 + icq * 4) = p;
    }
    __syncthreads();

    const int c = tid & 7, pxr = tid >> 3;
    u16* dstb = xb + ((size_t)(n * 4096) + px0) * 256 + ic0 + c * 8;
#pragma unroll
    for (int h = 0; h < 2; ++h) {
        int px = h * 32 + pxr;
        uint4 val = *(const uint4*)(t + px * 72 + c * 8);
        *(uint4*)(dstb + (size_t)px * 256) = val;
    }
}

// ---------------------------------------------------------------------------
// Kernel 0b: wgen v3 — coalesced. Each 16-lane group computes one dot64:
// lane c holds 4 elems (float4), 4 xor-shuffles reduce. Wave reads 1KB
// contiguous per load instr (was: 64 lanes x 64 separate rows).
// wb layout (stage-major): wb[s][oc][96] where s=(ic>>5)*3+kh,
// within-row offset = (tap%3)*32 + (ic&31).
// ---------------------------------------------------------------------------
__global__ __launch_bounds__(256) void wgen(const float* __restrict__ z,
                                            const float* __restrict__ W1,
                                            const float* __restrict__ B1,
                                            const float* __restrict__ W2,
                                            const float* __restrict__ B2,
                                            u16* __restrict__ wb) {
    __shared__ float zl[64];
    __shared__ float aL[1024];
    const int l = blockIdx.x, tid = threadIdx.x;
    if (tid < 64) zl[tid] = z[l * 64 + tid];
    __syncthreads();
    const int g = tid >> 4, c = tid & 15;
    const f32x4 zc = *(const f32x4*)(zl + c * 4);
    for (int it = 0; it < 64; ++it) {
        int r = it * 16 + g;                       // r = b*64+d
        f32x4 w = *(const f32x4*)(W1 + (size_t)r * 64 + c * 4);
        float p = w.x * zc.x + w.y * zc.y + w.z * zc.z + w.w * zc.w;
        if (c == 0) p += B1[r];
        p += __shfl_xor(p, 1); p += __shfl_xor(p, 2);
        p += __shfl_xor(p, 4); p += __shfl_xor(p, 8);
        if (c == 0) aL[r] = p;
    }
    __syncthreads();
    const int ob = l >> 4, ib = l & 15;
    for (int b1 = 0; b1 < 16; ++b1) {
        const f32x4 ac = *(const f32x4*)(aL + b1 * 64 + c * 4);  // broadcast
        const int ic = ib * 16 + b1;
#pragma unroll
        for (int it = 0; it < 9; ++it) {
            int kk = it * 16 + g;                  // 0..143 = b2*9+tap
            f32x4 w = *(const f32x4*)(W2 + (size_t)(b1 * 144 + kk) * 64 + c * 4);
            float p = w.x * ac.x + w.y * ac.y + w.z * ac.z + w.w * ac.w;
            if (c == 0) p += B2[b1 * 144 + kk];
            p += __shfl_xor(p, 1); p += __shfl_xor(p, 2);
            p += __shfl_xor(p, 4); p += __shfl_xor(p, 8);
            if (c == 0) {
                int b2 = kk / 9, tap = kk % 9;
                int oc = ob * 16 + b2;
                int s = (ic >> 5) * 3 + tap / 3;
                wb[(size_t)s * 24576 + oc * 96 + (tap % 3) * 32 + (ic & 31)] = f2bf(p);
            }
        }
    }
}

// ---------------------------------------------------------------------------
// Kernel 1: conv v3 — halo-staged K-loop. 24 stages (8 icb x 3 kh); per stage
// stage A[128oc][3tap*32ic] + B[2rows x 66px x 32ic] once, compute 3 taps
// (48 MFMA/wave per barrier-pair). LDS strides: A row 104 u16 (52dw==20mod32),
// B row 40 u16 (20dw) -> conflict-free-min ds_read_b128. Register prefetch of
// stage s+1 under compute. LDS 37.2 KB -> 4 blocks/CU by LDS.
// ---------------------------------------------------------------------------
__global__ __launch_bounds__(256) void conv_mfma(const u16* __restrict__ xb,
                                                 const u16* __restrict__ wb,
                                                 float* __restrict__ out) {
    __shared__ __align__(16) u16 As[128 * 104];   // 26.6 KB
    __shared__ __align__(16) u16 Bs[132 * 40];    // 10.6 KB

    const int tid = threadIdx.x, bid = blockIdx.x;
    const int xcd = bid & 7, rest = bid >> 3;
    const int mt = rest & 1, grp = rest >> 1;
    const int nt = grp * 8 + xcd;        // pixel tile 0..1023
    const int n = nt >> 5;
    const int h0 = (nt & 31) * 2;        // output rows h0, h0+1
    const int pimg = h0 * 64;
    const int oc0 = mt << 7;

    const int lane = tid & 63, wave = tid >> 6;
    const int wm = wave >> 1, wn = wave & 1;
    const int lr = lane & 15, lq = lane >> 4;

    // ---- A staging map: thread t -> row t>>1, half t&1, 6x16B contiguous
    const int arow = tid >> 1, ahalf = tid & 1;
    const u16* aptr = wb + (size_t)(oc0 + arow) * 96 + ahalf * 48;
    u16* alds = As + arow * 104 + ahalf * 48;

    // ---- B staging map: chunks q=tid, tid+256, (tid<16: 512+tid)
    int hrw[3], ldso[3]; bool vw[3]; long gbase[3];
#pragma unroll
    for (int k = 0; k < 3; ++k) {
        int q = (k == 0) ? tid : (k == 1) ? tid + 256 : 512 + tid;
        int prow = q >> 2, icc = q & 3;
        int hr = prow >= 66 ? 1 : 0;
        int w = prow - hr * 66 - 1;                // -1..64 (or junk if q>=528)
        hrw[k] = hr;
        vw[k] = (unsigned)w < 64u;
        gbase[k] = ((long)n * 4096 + w) * 256 + icc * 8;
        ldso[k] = prow * 40 + icc * 8;
    }

    f32x4 acc[4][4];
    const f32x4 z4 = {0.f, 0.f, 0.f, 0.f};
#pragma unroll
    for (int i = 0; i < 4; ++i)
#pragma unroll
        for (int j = 0; j < 4; ++j) acc[i][j] = z4;

    uint4 pa[6], pb[3];
    const uint4 zz = {0u, 0u, 0u, 0u};

    // prefetch stage 0 (icb=0, kh=0)
#pragma unroll
    for (int cc = 0; cc < 6; ++cc) pa[cc] = *(const uint4*)(aptr + cc * 8);
#pragma unroll
    for (int k = 0; k < 3; ++k) {
        int h = h0 + hrw[k] - 1;                   // + kh(=0)
        bool v = vw[k] && ((unsigned)h < 64u);
        pb[k] = v ? *(const uint4*)(xb + gbase[k] + (long)h * 16384) : zz;
    }

    int icb = 0, kh = 0;
    for (int s = 0; s < 24; ++s) {
        // commit prefetched stage to LDS
#pragma unroll
        for (int cc = 0; cc < 6; ++cc) *(uint4*)(alds + cc * 8) = pa[cc];
        *(uint4*)(Bs + ldso[0]) = pb[0];
        *(uint4*)(Bs + ldso[1]) = pb[1];
        if (tid < 16) *(uint4*)(Bs + ldso[2]) = pb[2];
        __syncthreads();

        // prefetch next stage
        int nkh = kh + 1, nicb = icb;
        if (nkh == 3) { nkh = 0; ++nicb; }
        if (s < 23) {
            const u16* ap = aptr + (size_t)(s + 1) * 24576;
#pragma unroll
            for (int cc = 0; cc < 6; ++cc) pa[cc] = *(const uint4*)(ap + cc * 8);
#pragma unroll
            for (int k = 0; k < 3; ++k) {
                int h = h0 + hrw[k] - 1 + nkh;
                bool v = vw[k] && ((unsigned)h < 64u);
                pb[k] = v ? *(const uint4*)(xb + gbase[k] + (long)h * 16384 + nicb * 32) : zz;
            }
        }

        // compute 3 taps from LDS
#pragma unroll
        for (int dwo = 0; dwo < 3; ++dwo) {
            short8 af[4], bf[4];
#pragma unroll
            for (int i = 0; i < 4; ++i)
                af[i] = *(const short8*)(As + (wm * 64 + i * 16 + lr) * 104 + dwo * 32 + lq * 8);
#pragma unroll
            for (int j = 0; j < 4; ++j)
                bf[j] = *(const short8*)(Bs + (wn * 66 + j * 16 + lr + dwo) * 40 + lq * 8);
#pragma unroll
            for (int i = 0; i < 4; ++i)
#pragma unroll
                for (int j = 0; j < 4; ++j)
                    acc[i][j] = __builtin_amdgcn_mfma_f32_16x16x32_bf16(
                        af[i], bf[j], acc[i][j], 0, 0, 0);
        }
        __syncthreads();
        icb = nicb; kh = nkh;
    }

    // epilogue: C/D layout col=lane&15 (pixel), row=lq*4+reg (oc)
    const size_t outn = (size_t)n * 256 * 4096;
#pragma unroll
    for (int i = 0; i < 4; ++i) {
        int ocb = oc0 + wm * 64 + i * 16 + lq * 4;
#pragma unroll
        for (int j = 0; j < 4; ++j) {
            int po = pimg + wn * 64 + j * 16 + lr;
            float* op = out + outn + (size_t)ocb * 4096 + po;
#pragma unroll
            for (int r = 0; r < 4; ++r) op[(size_t)r * 4096] = acc[i][j][r];
        }
    }
}

extern "C" void kernel_launch(void* const* d_in, const int* in_sizes, int n_in,
                              void* d_out, int out_size, void* d_ws, size_t ws_size,
                              hipStream_t stream) {
    const float* x  = (const float*)d_in[0];
    const float* z  = (const float*)d_in[1];
    const float* W1 = (const float*)d_in[2];
    const float* B1 = (const float*)d_in[3];
    const float* W2 = (const float*)d_in[4];
    const float* B2 = (const float*)d_in[5];
    float* out = (float*)d_out;

    u16* xb = (u16*)d_ws;                       // 32*4096*256 bf16 = 64 MiB
    u16* wb = xb + (size_t)32 * 4096 * 256;     // 24 stages * 256oc * 96 u16
    const size_t need = ((size_t)32 * 4096 * 256 + (size_t)24 * 256 * 96) * 2;
    if (ws_size < need) return;

    nchw2nhwc<<<dim3(8192), dim3(256), 0, stream>>>(x, xb);
    wgen<<<dim3(256), dim3(256), 0, stream>>>(z, W1, B1, W2, B2, wb);
    conv_mfma<<<dim3(2048), dim3(256), 0, stream>>>(xb, wb, out);
}